// Round 16
// baseline (44.924 us; speedup 1.0000x reference)
//
#include <hip/hip_runtime.h>
#include <math.h>

#define NEGV  (-1e30f)
#define LOG2E 1.44269504088896340736f
#define LN2   0.69314718055994530942f

typedef __attribute__((ext_vector_type(8))) _Float16 half8;
typedef __attribute__((ext_vector_type(2))) __fp16   fp16x2;  // cvt_pkrtz return type
typedef __attribute__((ext_vector_type(4))) float f32x4;

// Single-instruction base-2 transcendentals (v_exp_f32 / v_log_f32).
__device__ __forceinline__ float exp2_fast(float a) { return __builtin_amdgcn_exp2f(a); }
__device__ __forceinline__ float log2_fast(float a) { return __builtin_amdgcn_logf(a); }

// 8 fp32 -> 8 fp16 via v_cvt_pkrtz (4 VALU ops).
__device__ __forceinline__ half8 cvt8(float4 a, float4 b) {
    union { half8 v; fp16x2 p[4]; } u;
    u.p[0] = __builtin_amdgcn_cvt_pkrtz(a.x, a.y);
    u.p[1] = __builtin_amdgcn_cvt_pkrtz(a.z, a.w);
    u.p[2] = __builtin_amdgcn_cvt_pkrtz(b.x, b.y);
    u.p[3] = __builtin_amdgcn_cvt_pkrtz(b.z, b.w);
    return u.v;
}

// R15 structure with HALVED ds_read redundancy: one block = one batch,
// 128 threads = 2 waves; wave w owns g in [32w, 32w+32) (TWO 16-g tiles).
// Each wave reads the 8 B-fragments from LDS once and reuses them for both
// g-tiles in registers -> block-level ds_read falls 64 -> 32 b128, and
// phase-2 shuffle total halves. Everything else identical to R15 (44.4 us):
// fp16 LDS tile (row stride 144 B = 9x16B odd -> conflict-free b128), single
// fp16 MFMA per K-tile, log2-domain max-free softmax, exp2-reuse, inline
// theta/mw prep in the x-load shadow.
__global__ __launch_bounds__(128, 4) void mixed_logit_kernel(
    const float* __restrict__ x,      // [B,128,64]
    const int*   __restrict__ lens,   // [B]
    const float* __restrict__ theta,  // [64,64]
    const float* __restrict__ mw,     // [64]
    float* __restrict__ out)          // [B,128]
{
    __shared__ __align__(16) unsigned char xbuf[128 * 144];  // 18432 B
    __shared__ float red_s[2][128];                          // 1 KB

    const int tid  = threadIdx.x;
    const int lane = tid & 63;
    const int w    = tid >> 6;        // 0..1
    const int c15  = lane & 15;
    const int q    = lane >> 4;
    const int b    = blockIdx.x;
    const int len  = lens[b];

    // ---- x loads first: 16 coalesced float4 loads/thread (HBM starts now) ----
    float4 ra[16];
    {
        const float4* xp = (const float4*)(x + (size_t)b * 8192);
#pragma unroll
        for (int i = 0; i < 8; ++i) {
            const int j2 = (i << 7) + tid;        // pair idx
            ra[2 * i]     = xp[j2 * 2];
            ra[2 * i + 1] = xp[j2 * 2 + 1];
        }
    }

    // ---- inline theta/mw prep for BOTH g-tiles (overlaps x-load latency) ----
    half8 th[2][2];   // [j][kt], g-tile = 2w + j
    float wg[2][4];
    {
#pragma unroll
        for (int j = 0; j < 2; ++j) {
            const int gt = (w << 1) + j;
            const float* tr = theta + (size_t)((gt << 4) + c15) * 64 + (q << 3);
#pragma unroll
            for (int kt = 0; kt < 2; ++kt) {
                float4 a = *(const float4*)(tr + kt * 32);
                float4 c = *(const float4*)(tr + kt * 32 + 4);
                a.x *= LOG2E; a.y *= LOG2E; a.z *= LOG2E; a.w *= LOG2E;
                c.x *= LOG2E; c.y *= LOG2E; c.z *= LOG2E; c.w *= LOG2E;
                th[j][kt] = cvt8(a, c);
            }
        }
        const float mwl = mw[lane];
        float mmax = mwl;
#pragma unroll
        for (int s = 32; s >= 1; s >>= 1) mmax = fmaxf(mmax, __shfl_xor(mmax, s, 64));
        float me = __expf(mwl - mmax);
#pragma unroll
        for (int s = 32; s >= 1; s >>= 1) me += __shfl_xor(me, s, 64);
        const float logZ = mmax + __logf(me);
#pragma unroll
        for (int j = 0; j < 2; ++j) {
            const int gt = (w << 1) + j;
#pragma unroll
            for (int i = 0; i < 4; ++i)
                wg[j][i] = (mw[(gt << 4) + (q << 2) + i] - logZ) * LOG2E;
        }
    }

    // ---- cvt + stage into LDS ----
#pragma unroll
    for (int i = 0; i < 8; ++i) {
        const int j2 = (i << 7) + tid;   // row = j2>>3, p8 = j2&7
        const half8 h = cvt8(ra[2 * i], ra[2 * i + 1]);
        *(half8*)(xbuf + (j2 >> 3) * 144 + (j2 & 7) * 16) = h;
    }
    __syncthreads();

    // ---- GEMM: 8 N-tiles, fragments read ONCE, reused for both g-tiles ----
    f32x4 acc[2][8];
#pragma unroll
    for (int j = 0; j < 2; ++j)
#pragma unroll
        for (int nt = 0; nt < 8; ++nt) acc[j][nt] = (f32x4){0.f, 0.f, 0.f, 0.f};

#pragma unroll
    for (int nt = 0; nt < 8; ++nt) {
        const unsigned char* rb = xbuf + ((nt << 4) + c15) * 144 + (q << 4);
        const half8 x0 = *(const half8*)(rb);
        const half8 x1 = *(const half8*)(rb + 64);
#pragma unroll
        for (int j = 0; j < 2; ++j) {
            acc[j][nt] = __builtin_amdgcn_mfma_f32_16x16x32_f16(th[j][0], x0, acc[j][nt], 0, 0, 0);
            acc[j][nt] = __builtin_amdgcn_mfma_f32_16x16x32_f16(th[j][1], x1, acc[j][nt], 0, 0, 0);
        }
    }

    // ---- p = exp2(util), masked slots exactly 0 (computed ONCE, reused) ----
    bool vm[8];
#pragma unroll
    for (int nt = 0; nt < 8; ++nt) vm[nt] = ((nt << 4) + c15) < len;

#pragma unroll
    for (int j = 0; j < 2; ++j)
#pragma unroll
        for (int nt = 0; nt < 8; ++nt)
#pragma unroll
            for (int i = 0; i < 4; ++i) {
                const float pv = exp2_fast(acc[j][nt][i]);
                acc[j][nt][i] = vm[nt] ? pv : 0.f;
            }

    // ---- phase 1: denom over l per g; e4 = exp2(wg - lse2) ----
    float e4[2][4];
#pragma unroll
    for (int j = 0; j < 2; ++j)
#pragma unroll
        for (int i = 0; i < 4; ++i) {
            float e = 0.f;
#pragma unroll
            for (int nt = 0; nt < 8; ++nt) e += acc[j][nt][i];
#pragma unroll
            for (int s = 1; s < 16; s <<= 1) e += __shfl_xor(e, s, 64);
            e4[j][i] = exp2_fast(wg[j][i] - log2_fast(e));
        }

    // ---- phase 2: s2[nt] = sum over 32 g of p*e4; cross-q via shfl ----
#pragma unroll
    for (int nt = 0; nt < 8; ++nt) {
        float s2 = acc[0][nt][0] * e4[0][0];
        s2 = fmaf(acc[0][nt][1], e4[0][1], s2);
        s2 = fmaf(acc[0][nt][2], e4[0][2], s2);
        s2 = fmaf(acc[0][nt][3], e4[0][3], s2);
        s2 = fmaf(acc[1][nt][0], e4[1][0], s2);
        s2 = fmaf(acc[1][nt][1], e4[1][1], s2);
        s2 = fmaf(acc[1][nt][2], e4[1][2], s2);
        s2 = fmaf(acc[1][nt][3], e4[1][3], s2);
        s2 += __shfl_xor(s2, 16, 64);
        s2 += __shfl_xor(s2, 32, 64);
        if ((nt >> 1) == q) {           // static reg index, predicated write
            red_s[w][(nt << 4) + c15] = s2;
        }
    }
    __syncthreads();

    // ---- final: sum 2 wave-partials per l; log2 -> ln; finite sentinel ----
    {
        const int l = tid;              // all 128 threads
        const float S = red_s[0][l] + red_s[1][l];
        const float o = LN2 * log2_fast(S);
        out[(size_t)b * 128 + l] = (l < len) ? o : NEGV;
    }
}

extern "C" void kernel_launch(void* const* d_in, const int* in_sizes, int n_in,
                              void* d_out, int out_size, void* d_ws, size_t ws_size,
                              hipStream_t stream) {
    const float* x     = (const float*)d_in[0];
    const int*   lens  = (const int*)d_in[1];
    const float* theta = (const float*)d_in[2];
    const float* mw    = (const float*)d_in[3];
    float* out = (float*)d_out;
    const int B = in_sizes[1];  // 8192
    mixed_logit_kernel<<<B, 128, 0, stream>>>(x, lens, theta, mw, out);
}

// Round 17
// 44.627 us; speedup vs baseline: 1.0066x; 1.0066x over previous
//
#include <hip/hip_runtime.h>
#include <math.h>

#define NEGV  (-1e30f)
#define LOG2E 1.44269504088896340736f
#define LN2   0.69314718055994530942f

typedef __attribute__((ext_vector_type(8))) _Float16 half8;
typedef __attribute__((ext_vector_type(4))) _Float16 half4;
typedef __attribute__((ext_vector_type(2))) __fp16   fp16x2;  // cvt_pkrtz return type
typedef __attribute__((ext_vector_type(4))) float f32x4;

// Single-instruction base-2 transcendentals (v_exp_f32 / v_log_f32).
__device__ __forceinline__ float exp2_fast(float a) { return __builtin_amdgcn_exp2f(a); }
__device__ __forceinline__ float log2_fast(float a) { return __builtin_amdgcn_logf(a); }

// 8 fp32 -> 8 fp16 via v_cvt_pkrtz (4 VALU ops).
__device__ __forceinline__ half8 cvt8(float4 a, float4 b) {
    union { half8 v; fp16x2 p[4]; } u;
    u.p[0] = __builtin_amdgcn_cvt_pkrtz(a.x, a.y);
    u.p[1] = __builtin_amdgcn_cvt_pkrtz(a.z, a.w);
    u.p[2] = __builtin_amdgcn_cvt_pkrtz(b.x, b.y);
    u.p[3] = __builtin_amdgcn_cvt_pkrtz(b.z, b.w);
    return u.v;
}

// 4 fp32 -> 4 fp16 (8 B) via 2 cvt_pkrtz.
__device__ __forceinline__ half4 cvt4(float4 a) {
    union { half4 v; fp16x2 p[2]; } u;
    u.p[0] = __builtin_amdgcn_cvt_pkrtz(a.x, a.y);
    u.p[1] = __builtin_amdgcn_cvt_pkrtz(a.z, a.w);
    return u.v;
}

// R15 structure (44.4 us) with UNIT-STRIDE x loads.
// One block = one batch, 4 waves; wave w owns g in [16w,16w+16), all 128 l.
// x staged once in LDS as fp16 (row stride 144 B = 9x16B odd ->
// conflict-free-floor b128 fragment reads). Single fp16 MFMA per K-tile.
// Log2-domain max-free softmax; exp2-reuse; inline theta/mw prep in the
// x-load shadow; padded outputs get finite sentinel -1e30.
// NEW vs R15: x loads are DENSE unit-stride (thread tid reads float4 index
// (i<<8)+tid; each wave-instruction covers 1024 contiguous bytes = 16 cache
// lines fully used). R15's pair-loads had lanes strided 32 B -> each inst
// touched 32 lines half-used, doubling TA/L1 line-processing on 256 MB of
// streaming. Staging becomes 8x ds_write_b64 (2 lanes/bank = free).
__global__ __launch_bounds__(256, 6) void mixed_logit_kernel(
    const float* __restrict__ x,      // [B,128,64]
    const int*   __restrict__ lens,   // [B]
    const float* __restrict__ theta,  // [64,64]
    const float* __restrict__ mw,     // [64]
    float* __restrict__ out)          // [B,128]
{
    __shared__ __align__(16) unsigned char xbuf[128 * 144];  // 18432 B
    __shared__ float red_s[4][128];                          // 2 KB

    const int tid  = threadIdx.x;
    const int lane = tid & 63;
    const int w    = tid >> 6;
    const int c15  = lane & 15;
    const int q    = lane >> 4;
    const int b    = blockIdx.x;
    const int len  = lens[b];

    // ---- x loads first: 8 DENSE float4 loads (1 KiB/inst, 16 lines) ----
    float4 ra[8];
    {
        const float4* xp = (const float4*)(x + (size_t)b * 8192);
#pragma unroll
        for (int i = 0; i < 8; ++i)
            ra[i] = xp[(i << 8) + tid];
    }

    // ---- inline theta/mw prep (overlaps x-load latency; theta is L2-hot) ----
    half8 th[2];
    float wg[4];
    {
        const float* tr = theta + (size_t)((w << 4) + c15) * 64 + (q << 3);
#pragma unroll
        for (int kt = 0; kt < 2; ++kt) {
            float4 a = *(const float4*)(tr + kt * 32);
            float4 c = *(const float4*)(tr + kt * 32 + 4);
            a.x *= LOG2E; a.y *= LOG2E; a.z *= LOG2E; a.w *= LOG2E;
            c.x *= LOG2E; c.y *= LOG2E; c.z *= LOG2E; c.w *= LOG2E;
            th[kt] = cvt8(a, c);
        }
        const float mwl = mw[lane];
        float mmax = mwl;
#pragma unroll
        for (int s = 32; s >= 1; s >>= 1) mmax = fmaxf(mmax, __shfl_xor(mmax, s, 64));
        float me = __expf(mwl - mmax);
#pragma unroll
        for (int s = 32; s >= 1; s >>= 1) me += __shfl_xor(me, s, 64);
        const float logZ = mmax + __logf(me);
#pragma unroll
        for (int i = 0; i < 4; ++i)
            wg[i] = (mw[(w << 4) + (q << 2) + i] - logZ) * LOG2E;
    }

    // ---- cvt + stage into LDS: float4 j -> bytes [8*(j&15), +8) of row j>>4 ----
#pragma unroll
    for (int i = 0; i < 8; ++i) {
        const int j = (i << 8) + tid;
        *(half4*)(xbuf + (j >> 4) * 144 + (j & 15) * 8) = cvt4(ra[i]);
    }
    __syncthreads();

    // ---- GEMM: 8 N-tiles x 2 K-tiles, single fp16 MFMA each ----
    f32x4 acc[8];
#pragma unroll
    for (int nt = 0; nt < 8; ++nt) acc[nt] = (f32x4){0.f, 0.f, 0.f, 0.f};

#pragma unroll
    for (int nt = 0; nt < 8; ++nt) {
        const unsigned char* rb = xbuf + ((nt << 4) + c15) * 144 + (q << 4);
        const half8 x0 = *(const half8*)(rb);
        const half8 x1 = *(const half8*)(rb + 64);
        acc[nt] = __builtin_amdgcn_mfma_f32_16x16x32_f16(th[0], x0, acc[nt], 0, 0, 0);
        acc[nt] = __builtin_amdgcn_mfma_f32_16x16x32_f16(th[1], x1, acc[nt], 0, 0, 0);
    }

    // ---- p = exp2(util), masked slots exactly 0 (computed ONCE, reused) ----
#pragma unroll
    for (int nt = 0; nt < 8; ++nt) {
        const bool v = ((nt << 4) + c15) < len;
#pragma unroll
        for (int i = 0; i < 4; ++i) {
            const float pv = exp2_fast(acc[nt][i]);
            acc[nt][i] = v ? pv : 0.f;      // acc now holds p
        }
    }

    // ---- phase 1: denom over l per g (in-lane sum + shfl {1,2,4,8}) ----
    float e4[4];
#pragma unroll
    for (int i = 0; i < 4; ++i) {
        float e = 0.f;
#pragma unroll
        for (int nt = 0; nt < 8; ++nt) e += acc[nt][i];
#pragma unroll
        for (int s = 1; s < 16; s <<= 1) e += __shfl_xor(e, s, 64);
        e4[i] = exp2_fast(wg[i] - log2_fast(e));   // per-g scale factor
    }

    // ---- phase 2: s2[nt] = sum_i p[nt][i] * e4[i]; cross-q via shfl ----
#pragma unroll
    for (int nt = 0; nt < 8; ++nt) {
        float s2 = acc[nt][0] * e4[0];
        s2 = fmaf(acc[nt][1], e4[1], s2);
        s2 = fmaf(acc[nt][2], e4[2], s2);
        s2 = fmaf(acc[nt][3], e4[3], s2);
        s2 += __shfl_xor(s2, 16, 64);
        s2 += __shfl_xor(s2, 32, 64);
        if ((nt >> 1) == q) {           // static reg index, predicated write
            red_s[w][(nt << 4) + c15] = s2;
        }
    }
    __syncthreads();

    // ---- final: sum 4 wave-partials per l; log2 -> ln; finite sentinel ----
    if (tid < 128) {
        const int l = tid;
        const float S = red_s[0][l] + red_s[1][l] + red_s[2][l] + red_s[3][l];
        const float o = LN2 * log2_fast(S);
        out[(size_t)b * 128 + l] = (l < len) ? o : NEGV;
    }
}

extern "C" void kernel_launch(void* const* d_in, const int* in_sizes, int n_in,
                              void* d_out, int out_size, void* d_ws, size_t ws_size,
                              hipStream_t stream) {
    const float* x     = (const float*)d_in[0];
    const int*   lens  = (const int*)d_in[1];
    const float* theta = (const float*)d_in[2];
    const float* mw    = (const float*)d_in[3];
    float* out = (float*)d_out;
    const int B = in_sizes[1];  // 8192
    mixed_logit_kernel<<<B, 256, 0, stream>>>(x, lens, theta, mw, out);
}